// Round 3
// baseline (2525.832 us; speedup 1.0000x reference)
//
#include <hip/hip_runtime.h>

// Sinkhorn EMD, B=8, N=2048, eps=0.005, 50 iters.
// Single persistent kernel, 256 blocks x 1024 threads (1 block/CU —
// co-residency guaranteed: grid <= CU count, <=128 VGPR, 32.8KB LDS).
// Hand-rolled per-batch barriers (32 blocks/batch) with device-scope
// atomics + __threadfence (cross-XCD safe), monotonic counters.
// Log2 domain: K = eps*ln2; x_j = a_j + p.G_j (a_j=(pot_j-|g|^2)/K,
// G=2g/K); f_i = C1 + |p_i|^2 - K*LSE2_j(x).
// Passes 0..5: exact branchless online-rescale (2 exp/elem) — validated R1.
// Passes 6..99: fixed-shift M = row's previous LSE2 (1 exp/elem), clamp
// +100, sum floored -> self-correcting staircase if shift is off.

#define BB 8
#define NN 2048
#define NPASS 100
#define ONLINE_PASSES 6
#define RPW 4
#define BLOCKS_PER_BATCH 32
#define GRID_BLOCKS 256          // = CU count
#define TPB 1024                 // 16 waves

constexpr float EPSV = 0.005f;
constexpr float KS   = EPSV * 0.69314718055994531f; // eps*ln2
constexpr float INVK = 1.0f / KS;
constexpr float C1V  = -EPSV * 7.6246189861593985f; // eps*log(1/2048)
constexpr float K2Q  = KS * KS * 0.25f;             // rebuild |g|^2 from G

__device__ __forceinline__ float fexp2(float x) { return __builtin_amdgcn_exp2f(x); }
__device__ __forceinline__ float flog2(float x) { return __builtin_amdgcn_logf(x); }

// Monotonic-counter barrier: each participating block arrives once;
// everyone waits until *ctr >= target. Device-scope, fence both sides.
__device__ __forceinline__ void barrier_sync(int* ctr, int target) {
    __syncthreads();               // all waves' stores drained (vmcnt0 before s_barrier)
    if (threadIdx.x == 0) {
        __threadfence();           // agent-scope release (L2 writeback, cross-XCD)
        __hip_atomic_fetch_add(ctr, 1, __ATOMIC_ACQ_REL, __HIP_MEMORY_SCOPE_AGENT);
        while (__hip_atomic_load(ctr, __ATOMIC_ACQUIRE, __HIP_MEMORY_SCOPE_AGENT) < target) {
            __builtin_amdgcn_s_sleep(2);
        }
        __threadfence();           // agent-scope acquire (L1/L2 invalidate)
    }
    __syncthreads();
}

__global__ void __launch_bounds__(TPB, 4) emd_persist(
    const float* __restrict__ preds, const float* __restrict__ gts,
    float* __restrict__ fpot, float* __restrict__ gpot,
    float* __restrict__ partials, int* __restrict__ bctr, int* __restrict__ gctr,
    float* __restrict__ out)
{
    __shared__ float4 sj[NN];      // {Gx, Gy, Gz, a}
    __shared__ float wred[16];

    const int blk  = blockIdx.x;
    const int b    = blk >> 5;                 // 32 blocks per batch
    const int rb   = blk & 31;
    const int wave = threadIdx.x >> 6;
    const int lane = threadIdx.x & 63;
    const int row0 = rb * 64 + wave * RPW;     // 64 rows per block

    const float* pb  = preds + (size_t)b * NN * 3;
    const float* gbp = gts   + (size_t)b * NN * 3;
    float* fb = fpot + (size_t)b * NN;
    float* gb = gpot + (size_t)b * NN;
    int*   bar = bctr + b * 32;                // own cache line per batch

#pragma unroll 1
    for (int pass = 0; pass < NPASS; ++pass) {
        const int odd = pass & 1;
        const float* cpts = odd ? pb  : gbp;
        const float* rpts = odd ? gbp : pb;
        const float* pin  = odd ? fb  : gb;
        float*       pout = odd ? gb  : fb;

        // stage cols: {2g/K, (pot - |g|^2)/K}
        for (int t = threadIdx.x; t < NN; t += TPB) {
            float gx = cpts[3*t], gy = cpts[3*t+1], gz = cpts[3*t+2];
            float n2 = gx*gx + gy*gy + gz*gz;
            sj[t] = make_float4(gx*(2.f*INVK), gy*(2.f*INVK), gz*(2.f*INVK),
                                (pin[t] - n2) * INVK);
        }
        __syncthreads();

        float px[RPW], py[RPW], pz[RPW], pn[RPW];
#pragma unroll
        for (int r = 0; r < RPW; ++r) {
            int i = row0 + r;
            px[r] = rpts[3*i]; py[r] = rpts[3*i+1]; pz[r] = rpts[3*i+2];
            pn[r] = px[r]*px[r] + py[r]*py[r] + pz[r]*pz[r];
        }

        if (pass < ONLINE_PASSES) {
            // exact branchless online-rescale (2 exp/elem)
            float m[RPW], s[RPW];
#pragma unroll
            for (int r = 0; r < RPW; ++r) { m[r] = -1e30f; s[r] = 0.f; }
#pragma unroll 4
            for (int c = 0; c < NN/64; ++c) {
                float4 d = sj[c*64 + lane];
#pragma unroll
                for (int r = 0; r < RPW; ++r) {
                    float x  = fmaf(px[r], d.x, fmaf(py[r], d.y, fmaf(pz[r], d.z, d.w)));
                    float mn = fmaxf(m[r], x);
                    s[r] = fmaf(s[r], fexp2(m[r]-mn), fexp2(x-mn));
                    m[r] = mn;
                }
            }
#pragma unroll
            for (int r = 0; r < RPW; ++r) {
                float mm = m[r], ss = s[r];
                for (int off = 1; off < 64; off <<= 1) {
                    float mo = __shfl_xor(mm, off, 64);
                    float so = __shfl_xor(ss, off, 64);
                    float mn = fmaxf(mm, mo);
                    ss = fmaf(ss, fexp2(mm-mn), so * fexp2(mo-mn));
                    mm = mn;
                }
                if (lane == 0)
                    pout[row0+r] = C1V + pn[r] - KS * (mm + flog2(fmaxf(ss, 1e-37f)));
            }
        } else {
            // fixed-shift: M = row's previous LSE2 (from its own old potential)
            float M[RPW], s[RPW];
#pragma unroll
            for (int r = 0; r < RPW; ++r) {
                float prev = pout[row0+r];
                M[r] = (C1V + pn[r] - prev) * INVK;
                s[r] = 0.f;
            }
#pragma unroll 4
            for (int c = 0; c < NN/64; ++c) {
                float4 d = sj[c*64 + lane];
#pragma unroll
                for (int r = 0; r < RPW; ++r) {
                    float x = fmaf(px[r], d.x, fmaf(py[r], d.y, fmaf(pz[r], d.z, d.w)));
                    s[r] += fexp2(fminf(x - M[r], 100.f));
                }
            }
#pragma unroll
            for (int r = 0; r < RPW; ++r) {
                float ss = s[r];
                for (int off = 1; off < 64; off <<= 1) ss += __shfl_xor(ss, off, 64);
                if (lane == 0)
                    pout[row0+r] = C1V + pn[r] - KS * (M[r] + flog2(fmaxf(ss, 1e-37f)));
            }
        }
        barrier_sync(bar, 32 * (pass + 1));
    }

    // ---- dis: sum P*C ----
    for (int t = threadIdx.x; t < NN; t += TPB) {
        float gx = gbp[3*t], gy = gbp[3*t+1], gz = gbp[3*t+2];
        float n2 = gx*gx + gy*gy + gz*gz;
        sj[t] = make_float4(gx*(2.f*INVK), gy*(2.f*INVK), gz*(2.f*INVK),
                            (gb[t] - n2) * INVK);
    }
    __syncthreads();

    float px[RPW], py[RPW], pz[RPW], pn[RPW], bb2[RPW], acc[RPW];
#pragma unroll
    for (int r = 0; r < RPW; ++r) {
        int i = row0 + r;
        px[r] = pb[3*i]; py[r] = pb[3*i+1]; pz[r] = pb[3*i+2];
        pn[r] = px[r]*px[r] + py[r]*py[r] + pz[r]*pz[r];
        bb2[r] = (fb[i] - pn[r]) * INVK;
        acc[r] = 0.f;
    }
#pragma unroll 4
    for (int c = 0; c < NN/64; ++c) {
        float4 d = sj[c*64 + lane];
        float gn = K2Q * (d.x*d.x + d.y*d.y + d.z*d.z);  // |g|^2 rebuilt
#pragma unroll
        for (int r = 0; r < RPW; ++r) {
            float dot = fmaf(px[r], d.x, fmaf(py[r], d.y, pz[r]*d.z));
            float y   = dot + d.w + bb2[r];              // log2 P
            float e   = fexp2(fminf(y, 80.f));
            float Cc  = fmaf(-KS, dot, pn[r] + gn);
            acc[r] = fmaf(e, Cc, acc[r]);
        }
    }
    float tot = acc[0] + acc[1] + acc[2] + acc[3];
    for (int off = 1; off < 64; off <<= 1) tot += __shfl_xor(tot, off, 64);
    if (lane == 0) wred[wave] = tot;
    __syncthreads();
    if (threadIdx.x == 0) {
        float v = 0.f;
        for (int w = 0; w < 16; ++w) v += wred[w];
        partials[blk] = v;
    }

    barrier_sync(gctr, GRID_BLOCKS);   // full-grid barrier (once)

    if (blk == 0) {
        float v = (threadIdx.x < GRID_BLOCKS) ? partials[threadIdx.x] : 0.f;
        for (int off = 1; off < 64; off <<= 1) v += __shfl_xor(v, off, 64);
        if (lane == 0) wred[wave] = v;
        __syncthreads();
        if (threadIdx.x == 0) {
            float t2 = 0.f;
            for (int w = 0; w < 16; ++w) t2 += wred[w];
            out[0] = t2 * (1.0f / BB);
        }
    }
}

extern "C" void kernel_launch(void* const* d_in, const int* in_sizes, int n_in,
                              void* d_out, int out_size, void* d_ws, size_t ws_size,
                              hipStream_t stream) {
    const float* preds = (const float*)d_in[0];
    const float* gts   = (const float*)d_in[1];
    float* fp       = (float*)d_ws;              // [B*N]
    float* gp       = fp + BB * NN;              // [B*N]
    float* partials = gp + BB * NN;              // [256]
    int*   bctr     = (int*)(partials + GRID_BLOCKS); // 8 batches x 32-int lines
    int*   gctr     = bctr + BB * 32;            // [32]
    float* out      = (float*)d_out;

    // zero potentials + partials + all barrier counters (ws is 0xAA-poisoned)
    size_t zbytes = (size_t)(2 * BB * NN + GRID_BLOCKS) * sizeof(float)
                  + (size_t)(BB * 32 + 32) * sizeof(int);
    hipMemsetAsync(d_ws, 0, zbytes, stream);

    emd_persist<<<dim3(GRID_BLOCKS), dim3(TPB), 0, stream>>>(
        preds, gts, fp, gp, partials, bctr, gctr, out);
}